// Round 3
// baseline (1369.900 us; speedup 1.0000x reference)
//
#include <hip/hip_runtime.h>

typedef unsigned short u16;
typedef __attribute__((ext_vector_type(8))) short short8;
typedef __attribute__((ext_vector_type(4))) float floatx4;

// ---------- bf16 helpers (RNE) ----------
__device__ __forceinline__ float bf2f(u16 u) {
    return __uint_as_float(((unsigned int)u) << 16);
}
__device__ __forceinline__ u16 f2bf(float f) {
    unsigned int i = __float_as_uint(f);
    unsigned int r = i + 0x7FFFu + ((i >> 16) & 1u);
    return (u16)(r >> 16);
}

// ---------- async global->LDS (16B per lane, wave-uniform LDS base) ----------
typedef __attribute__((address_space(3))) void lds_void;
typedef const __attribute__((address_space(1))) void g_void;
__device__ __forceinline__ void async_copy16(const void* g, void* l) {
    __builtin_amdgcn_global_load_lds((g_void*)g, (lds_void*)l, 16, 0, 0);
}

#define MFMA16(a, b, c) __builtin_amdgcn_mfma_f32_16x16x32_bf16(a, b, c, 0, 0, 0)

// ================= problem constants =================
#define E_BONDS 131072
#define N_ATOMS_C 65536
#define KPAD_I 160     // 157 padded
#define KPAD_O 416     // 399 padded
#define N_MOLS 2048

// epilogue slice: 16 rows x 264 u16 (528B stride, 16B-aligned rows, conflict-padded)
#define EPI_RSTR 264
#define EPI_SLICE_B 8448

// ================= prep kernels =================
__global__ __launch_bounds__(256) void prep_fbonds(const float* __restrict__ fb, u16* __restrict__ out) {
    int idx = blockIdx.x * 256 + threadIdx.x;           // E*160 total
    int row = idx / KPAD_I;
    int col = idx - row * KPAD_I;
    float v = (col < 157) ? fb[(size_t)row * 157 + col] : 0.f;
    out[idx] = f2bf(v);
}

// W [K,256] f32 -> Wt [256, Kpad] bf16 (transposed, zero-padded)
__global__ __launch_bounds__(256) void prep_wt(const float* __restrict__ W, u16* __restrict__ Wt, int K, int Kpad) {
    int idx = blockIdx.x * 256 + threadIdx.x;           // 256*Kpad total
    int n = idx / Kpad;
    int k = idx - n * Kpad;
    float v = (k < K) ? W[(size_t)k * 256 + n] : 0.f;
    Wt[idx] = f2bf(v);
}

// W_o_w [399,256] -> reordered transposed [256,416]
__global__ __launch_bounds__(256) void prep_wo(const float* __restrict__ W, u16* __restrict__ Wt) {
    int idx = blockIdx.x * 256 + threadIdx.x;           // 256*416 total
    int n = idx / KPAD_O;
    int k = idx - n * KPAD_O;
    float v = 0.f;
    if (k < 256)      v = W[(size_t)(143 + k) * 256 + n];
    else if (k < 399) v = W[(size_t)(k - 256) * 256 + n];
    Wt[idx] = f2bf(v);
}

// ================= MFMA GEMM, N=256 full width: C[M,256] = epi(A[M,K] @ Bt[256,K]^T) =================
// EPI: 0 plain->out ; 1 out2=pre, out=relu(pre), tout=relu.Wma score ; 3 out=relu(acc+bias)
// block: 256 thr (4 waves x 32 rows), M-tile 128, all 256 cols per block.
template <int EPI>
__global__ __launch_bounds__(256, 2) void gemm256(
    const u16* __restrict__ A, const u16* __restrict__ Bt,
    u16* __restrict__ out, u16* __restrict__ out2,
    const float* __restrict__ bias, const float* __restrict__ wma,
    float* __restrict__ tout, int K)
{
    __shared__ char ldsbuf[33792];     // stage: Al 8192 + Bl 16384 = 24576 ; epi: 4 x 8448 = 33792
    u16* Al = (u16*)ldsbuf;
    u16* Bl = (u16*)(ldsbuf + 8192);

    const int tid = threadIdx.x;
    const int w = tid >> 6, lane = tid & 63;
    const int quad = lane >> 4, mr = lane & 15;
    const int m0 = blockIdx.x * 128;

    floatx4 acc[2][16] = {};

    for (int k0 = 0; k0 < K; k0 += 32) {
        // stage A: 512 chunks of 16B
        {
            int c = tid;
            async_copy16(A + (size_t)(m0 + (c & 127)) * K + k0 + ((c >> 7) << 3), Al + c * 8);
            c = tid + 256;
            async_copy16(A + (size_t)(m0 + (c & 127)) * K + k0 + ((c >> 7) << 3), Al + c * 8);
        }
        // stage B: 1024 chunks
#pragma unroll
        for (int i = 0; i < 4; ++i) {
            int c = tid + i * 256;
            async_copy16(Bt + (size_t)(c & 255) * K + k0 + ((c >> 8) << 3), Bl + c * 8);
        }
        __syncthreads();

        short8 a0 = *(const short8*)(Al + quad * 1024 + (w * 32 + mr) * 8);
        short8 a1 = *(const short8*)(Al + quad * 1024 + (w * 32 + 16 + mr) * 8);
#pragma unroll
        for (int j = 0; j < 16; ++j) {
            short8 bf = *(const short8*)(Bl + quad * 2048 + (j * 16 + mr) * 8);
            acc[0][j] = MFMA16(a0, bf, acc[0][j]);
            acc[1][j] = MFMA16(a1, bf, acc[1][j]);
        }
        __syncthreads();
    }

    // ---- coalesced epilogue via per-wave LDS transpose ----
    u16* slice = (u16*)(ldsbuf + w * EPI_SLICE_B);
    const int lhalf = lane >> 5;
    const int lcol = (lane & 31) * 8;
    float wmal8[8];
    if (EPI == 1) {
#pragma unroll
        for (int e = 0; e < 8; ++e) wmal8[e] = wma[lcol + e];
    }
    float bl16[16];
    if (EPI == 3) {
#pragma unroll
        for (int j = 0; j < 16; ++j) bl16[j] = bias[j * 16 + mr];
    }

#pragma unroll
    for (int rg = 0; rg < 2; ++rg) {
        // scatter acc (MFMA C-layout) into the wave-private slice as bf16
#pragma unroll
        for (int j = 0; j < 16; ++j)
#pragma unroll
            for (int r = 0; r < 4; ++r) {
                float v = acc[rg][j][r];
                if (EPI == 3) { v += bl16[j]; v = v > 0.f ? v : 0.f; }
                slice[(quad * 4 + r) * EPI_RSTR + j * 16 + mr] = f2bf(v);
            }
        // contiguous readback + 16B stores
#pragma unroll
        for (int round = 0; round < 8; ++round) {
            int rowl = round * 2 + lhalf;
            int row = m0 + w * 32 + rg * 16 + rowl;
            size_t off = (size_t)row * 256 + lcol;
            short8 pv = *(const short8*)(slice + rowl * EPI_RSTR + lcol);
            if (EPI == 0 || EPI == 3) {
                *(short8*)(out + off) = pv;
            } else {  // EPI 1
                *(short8*)(out2 + off) = pv;
                short8 rv; float p = 0.f;
#pragma unroll
                for (int e = 0; e < 8; ++e) {
                    u16 u = (u16)pv[e];
                    u = (u & 0x8000u) ? (u16)0 : u;     // relu in bf16 domain
                    rv[e] = (short)u;
                    p += bf2f(u) * wmal8[e];
                }
                *(short8*)(out + off) = rv;
                p += __shfl_xor(p, 1); p += __shfl_xor(p, 2); p += __shfl_xor(p, 4);
                p += __shfl_xor(p, 8); p += __shfl_xor(p, 16);
                if ((lane & 31) == 0) tout[row] = p;
            }
        }
    }
}

// ================= fused iteration: msg_out = relu(binput + attn_gather(msg_in) @ W_h), t_out = msg_out . Wma =================
// block: 512 thr (8 waves x 16 rows = 128 rows). W_h staged in two 64KB halves.
// acc = 64 regs/wave -> 16 waves/CU at VGPR<=128, 2 blocks/CU at 67.6KB LDS.
__global__ __launch_bounds__(512, 4) void fused_iter(
    const u16* __restrict__ msg_in, const float* __restrict__ t_in,
    const int* __restrict__ bgraph, const u16* __restrict__ wth,
    const u16* __restrict__ binput, u16* __restrict__ msg_out,
    float* __restrict__ t_out, const float* __restrict__ wma)
{
    __shared__ char ldsbuf[67584];   // stage: 64KB (one W_h half: [kb2'=16][n=256][8]) ; epi: 8 x 8448
    u16* Bl = (u16*)ldsbuf;

    const int tid = threadIdx.x;
    const int w = tid >> 6, lane = tid & 63;
    const int quad = lane >> 4, mr = lane & 15;
    const int m0 = blockIdx.x * 128;

    // stage W_h half 0 (k 0..127) — overlaps the gather below
#pragma unroll
    for (int i = 0; i < 8; ++i) {
        int c = tid + i * 512;
        async_copy16(wth + (size_t)(c & 255) * 256 + ((c >> 8) << 3), Bl + c * 8);
    }

    // gather + softmax-attention directly into MFMA A-fragments
    // lane (quad,mr) of wave w serves row m0 + w*16 + mr, k-chunk quad*8 within each 32-k step
    short8 afrag[8];
    {
        int row = m0 + w * 16 + mr;
        const int* bg = bgraph + (size_t)row * 6;
        int2 b01 = *(const int2*)bg;
        int2 b23 = *(const int2*)(bg + 2);
        int2 b45 = *(const int2*)(bg + 4);
        int b[6] = {b01.x, b01.y, b23.x, b23.y, b45.x, b45.y};
        float s[6];
#pragma unroll
        for (int j = 0; j < 6; ++j) s[j] = t_in[b[j]];
        float mx = fmaxf(fmaxf(fmaxf(s[0], s[1]), fmaxf(s[2], s[3])), fmaxf(s[4], s[5]));
        float wg[6]; float den = 0.f;
#pragma unroll
        for (int j = 0; j < 6; ++j) { wg[j] = __expf(s[j] - mx); den += wg[j]; }
        float inv = 1.f / den;
#pragma unroll
        for (int j = 0; j < 6; ++j) wg[j] *= inv;

#pragma unroll
        for (int kh = 0; kh < 2; ++kh) {   // halves of the 8 k-blocks (reg pressure)
            float a8[4][8] = {};
#pragma unroll
            for (int j = 0; j < 6; ++j) {
                float wj = wg[j];
#pragma unroll
                for (int q2 = 0; q2 < 4; ++q2) {
                    uint4 u = *(const uint4*)(msg_in + (size_t)b[j] * 256 + (kh * 4 + q2) * 32 + quad * 8);
                    a8[q2][0] += wj * __uint_as_float(u.x << 16);
                    a8[q2][1] += wj * __uint_as_float(u.x & 0xffff0000u);
                    a8[q2][2] += wj * __uint_as_float(u.y << 16);
                    a8[q2][3] += wj * __uint_as_float(u.y & 0xffff0000u);
                    a8[q2][4] += wj * __uint_as_float(u.z << 16);
                    a8[q2][5] += wj * __uint_as_float(u.z & 0xffff0000u);
                    a8[q2][6] += wj * __uint_as_float(u.w << 16);
                    a8[q2][7] += wj * __uint_as_float(u.w & 0xffff0000u);
                }
            }
#pragma unroll
            for (int q2 = 0; q2 < 4; ++q2) {
                short8 fr;
#pragma unroll
                for (int e = 0; e < 8; ++e) fr[e] = (short)f2bf(a8[q2][e]);
                afrag[kh * 4 + q2] = fr;
            }
        }
    }

    __syncthreads();   // W_h half 0 staged, gathers done

    floatx4 acc[16] = {};
#pragma unroll
    for (int ks = 0; ks < 4; ++ks) {
#pragma unroll
        for (int j = 0; j < 16; ++j) {
            short8 bf = *(const short8*)(Bl + (ks * 4 + quad) * 2048 + (j * 16 + mr) * 8);
            acc[j] = MFMA16(afrag[ks], bf, acc[j]);
        }
    }
    __syncthreads();   // all waves done reading half 0

    // stage W_h half 1 (k 128..255)
#pragma unroll
    for (int i = 0; i < 8; ++i) {
        int c = tid + i * 512;
        async_copy16(wth + (size_t)(c & 255) * 256 + 128 + ((c >> 8) << 3), Bl + c * 8);
    }
    __syncthreads();

#pragma unroll
    for (int ks = 4; ks < 8; ++ks) {
#pragma unroll
        for (int j = 0; j < 16; ++j) {
            short8 bf = *(const short8*)(Bl + ((ks - 4) * 4 + quad) * 2048 + (j * 16 + mr) * 8);
            acc[j] = MFMA16(afrag[ks], bf, acc[j]);
        }
    }
    __syncthreads();   // before LDS reuse by epilogue

    // ---- coalesced epilogue: +binput, relu, 16B stores, score ----
    u16* slice = (u16*)(ldsbuf + w * EPI_SLICE_B);
    const int lhalf = lane >> 5;
    const int lcol = (lane & 31) * 8;
    float wmal8[8];
#pragma unroll
    for (int e = 0; e < 8; ++e) wmal8[e] = wma[lcol + e];

#pragma unroll
    for (int j = 0; j < 16; ++j)
#pragma unroll
        for (int r = 0; r < 4; ++r)
            slice[(quad * 4 + r) * EPI_RSTR + j * 16 + mr] = f2bf(acc[j][r]);

#pragma unroll
    for (int round = 0; round < 8; ++round) {
        int rowl = round * 2 + lhalf;
        int row = m0 + w * 16 + rowl;
        size_t off = (size_t)row * 256 + lcol;
        short8 av = *(const short8*)(slice + rowl * EPI_RSTR + lcol);
        short8 bv = *(const short8*)(binput + off);
        short8 mv; float p = 0.f;
#pragma unroll
        for (int e = 0; e < 8; ++e) {
            float v = bf2f((u16)av[e]) + bf2f((u16)bv[e]);
            v = v > 0.f ? v : 0.f;
            u16 q = f2bf(v);
            mv[e] = (short)q;
            p += bf2f(q) * wmal8[e];
        }
        *(short8*)(msg_out + off) = mv;
        p += __shfl_xor(p, 1); p += __shfl_xor(p, 2); p += __shfl_xor(p, 4);
        p += __shfl_xor(p, 8); p += __shfl_xor(p, 16);
        if ((lane & 31) == 0) t_out[row] = p;
    }
}

// ================= atom aggregation -> ainput [N,416] = [nei_a(256) | fatoms(143) | 0(17)] =================
__global__ __launch_bounds__(256) void atom_agg(const u16* __restrict__ message, const int* __restrict__ agraph,
                                                const float* __restrict__ fatoms, u16* __restrict__ ainput) {
    int wave = threadIdx.x >> 6, lane = threadIdx.x & 63;
    int a = blockIdx.x * 4 + wave;
    const int* ag = agraph + (size_t)a * 6;
    float a0 = 0, a1 = 0, a2 = 0, a3 = 0;
#pragma unroll
    for (int j = 0; j < 6; ++j) {
        int b = ag[j];
        ushort4 u = *(const ushort4*)(message + (size_t)b * 256 + lane * 4);
        a0 += bf2f(u.x); a1 += bf2f(u.y); a2 += bf2f(u.z); a3 += bf2f(u.w);
    }
    u16* arow = ainput + (size_t)a * KPAD_O;
    ushort4 o; o.x = f2bf(a0); o.y = f2bf(a1); o.z = f2bf(a2); o.w = f2bf(a3);
    *(ushort4*)(arow + lane * 4) = o;
    const float* frow = fatoms + (size_t)a * 143;
    for (int c = lane; c < 143; c += 64) arow[256 + c] = f2bf(frow[c]);
    if (lane < 17) arow[399 + lane] = 0;
}

// ================= per-molecule self-attention: z = softmax(hW @ h^T) @ h =================
#define HSTR 260
__global__ __launch_bounds__(256) void mol_attn(const u16* __restrict__ atomh, const u16* __restrict__ hWg,
                                                u16* __restrict__ z) {
    __shared__ float hs[32 * HSTR];
    __shared__ float P[32 * 33];
    const int t = threadIdx.x;
    const int b = blockIdx.x;
    const u16* hbase = atomh + (size_t)b * 32 * 256;
    for (int e0 = t * 4; e0 < 8192; e0 += 1024) {
        int row = e0 >> 8, col = e0 & 255;
        ushort4 u = *(const ushort4*)(hbase + e0);
        floatx4 v; v.x = bf2f(u.x); v.y = bf2f(u.y); v.z = bf2f(u.z); v.w = bf2f(u.w);
        *(floatx4*)&hs[row * HSTR + col] = v;
    }
    __syncthreads();

    {
        int c = t & 31, a0 = t >> 5;
        const u16* hWb = hWg + (size_t)b * 32 * 256;
        for (int r = 0; r < 4; ++r) {
            int a = a0 + r * 8;
            const u16* hwrow = hWb + a * 256;
            float s = 0.f;
            for (int d = 0; d < 256; d += 4) {
                ushort4 u = *(const ushort4*)(hwrow + d);
                const float* hp = &hs[c * HSTR + d];
                s += bf2f(u.x) * hp[0] + bf2f(u.y) * hp[1] + bf2f(u.z) * hp[2] + bf2f(u.w) * hp[3];
            }
            P[a * 33 + c] = s;
        }
    }
    __syncthreads();
    if (t < 32) {
        float* prow = &P[t * 33];
        float mx = prow[0];
        for (int i = 1; i < 32; ++i) mx = fmaxf(mx, prow[i]);
        float den = 0.f;
        for (int i = 0; i < 32; ++i) { float ev = __expf(prow[i] - mx); prow[i] = ev; den += ev; }
        float inv = 1.f / den;
        for (int i = 0; i < 32; ++i) prow[i] *= inv;
    }
    __syncthreads();

    {
        int a = t >> 3, q = t & 7;
        floatx4 acc8[8];
#pragma unroll
        for (int i = 0; i < 8; ++i) acc8[i] = (floatx4){0.f, 0.f, 0.f, 0.f};
        const float* prow = &P[a * 33];
        for (int cc = 0; cc < 32; ++cc) {
            float p = prow[cc];
            const float* hrow = &hs[cc * HSTR + q * 4];
#pragma unroll
            for (int i = 0; i < 8; ++i) {
                floatx4 hv = *(const floatx4*)(hrow + i * 32);
                acc8[i] += p * hv;
            }
        }
        u16* zrow = z + ((size_t)b * 32 + a) * 256 + q * 4;
#pragma unroll
        for (int i = 0; i < 8; ++i) {
            ushort4 o;
            o.x = f2bf(acc8[i].x); o.y = f2bf(acc8[i].y); o.z = f2bf(acc8[i].z); o.w = f2bf(acc8[i].w);
            *(ushort4*)(zrow + i * 32) = o;
        }
    }
}

// ================= final: out[b,d] = sum_a (h + att_h) / 32 =================
__global__ __launch_bounds__(256) void final_reduce(const u16* __restrict__ atomh, const u16* __restrict__ atth,
                                                    float* __restrict__ out) {
    int idx = blockIdx.x * 256 + threadIdx.x;   // 2048*256
    int b = idx >> 8, d = idx & 255;
    const u16* ph = atomh + ((size_t)b * 32) * 256 + d;
    const u16* pa = atth + ((size_t)b * 32) * 256 + d;
    float s = 0.f;
#pragma unroll 4
    for (int a = 0; a < 32; ++a) s += bf2f(ph[a * 256]) + bf2f(pa[a * 256]);
    out[idx] = s * 0.03125f;
}

// ================= workspace layout (bytes) =================
#define O_FBP      ((size_t)0)                        // 41,943,040  fbp -> later atomh (33.5MB)
#define O_BINPUT   ((size_t)41943040)                 // 67,108,864  binput -> later hW (+0), zbuf (+33,554,432)
#define O_MSGA     ((size_t)109051904)                // 67,108,864  msg ping -> later ainput (54.5MB)
#define O_MSGB     ((size_t)176160768)                // 67,108,864  msg pong -> later atth (33.5MB)
#define O_W        ((size_t)243269632)
#define O_WTI      (O_W)                              // 81,920
#define O_WTH      (O_W + 81920)                      // 131,072
#define O_WTO      (O_W + 212992)                     // 212,992
#define O_WTA      (O_W + 425984)                     // 131,072
#define O_WTB      (O_W + 557056)                     // 131,072
#define WS_NEED    ((size_t)243957760)

extern "C" void kernel_launch(void* const* d_in, const int* in_sizes, int n_in,
                              void* d_out, int out_size, void* d_ws, size_t ws_size,
                              hipStream_t stream) {
    const float* fatoms = (const float*)d_in[0];
    const float* fbonds = (const float*)d_in[1];
    const int*   agraph = (const int*)d_in[2];
    const int*   bgraph = (const int*)d_in[3];
    const float* W_i    = (const float*)d_in[5];
    const float* W_h    = (const float*)d_in[6];
    const float* W_o_w  = (const float*)d_in[7];
    const float* W_o_b  = (const float*)d_in[8];
    const float* W_a    = (const float*)d_in[9];
    const float* W_b_w  = (const float*)d_in[10];
    const float* W_b_b  = (const float*)d_in[11];
    const float* W_ma1  = (const float*)d_in[12];
    float* out = (float*)d_out;

    if (ws_size < WS_NEED) return;

    char* ws = (char*)d_ws;
    u16* fbp     = (u16*)(ws + O_FBP);
    u16* binput  = (u16*)(ws + O_BINPUT);
    u16* msgA    = (u16*)(ws + O_MSGA);
    u16* msgB    = (u16*)(ws + O_MSGB);
    u16* wti     = (u16*)(ws + O_WTI);
    u16* wth     = (u16*)(ws + O_WTH);
    u16* wto     = (u16*)(ws + O_WTO);
    u16* wta     = (u16*)(ws + O_WTA);
    u16* wtb     = (u16*)(ws + O_WTB);
    // aliases (dead-buffer reuse)
    u16* ainput  = (u16*)(ws + O_MSGA);     // msg2 dead after iter3
    u16* atomh   = (u16*)(ws + O_FBP);      // fbp dead after binput GEMM
    u16* hW      = (u16*)(ws + O_BINPUT);   // binput dead after iter3
    u16* zbuf    = (u16*)(ws + O_BINPUT + 33554432);
    u16* atth    = (u16*)(ws + O_MSGB);     // msg3 dead after atom_agg
    // t score ping-pong lives in d_out (1MB of 2MB; overwritten by final_reduce)
    float* tA = (float*)d_out;
    float* tB = tA + E_BONDS;

    // prep
    prep_fbonds<<<81920, 256, 0, stream>>>(fbonds, fbp);
    prep_wt<<<160, 256, 0, stream>>>(W_i, wti, 157, KPAD_I);
    prep_wt<<<256, 256, 0, stream>>>(W_h, wth, 256, 256);
    prep_wo<<<416, 256, 0, stream>>>(W_o_w, wto);
    prep_wt<<<256, 256, 0, stream>>>(W_a, wta, 256, 256);
    prep_wt<<<256, 256, 0, stream>>>(W_b_w, wtb, 256, 256);

    // binput = fbonds @ W_i ; msg0 = relu(binput) ; t0 = msg0 . Wma
    gemm256<1><<<1024, 256, 0, stream>>>(fbp, wti, msgA, binput, nullptr, W_ma1, tA, KPAD_I);

    // 3 fused message-passing iterations (gather+attn+GEMM+score in one kernel)
    fused_iter<<<1024, 512, 0, stream>>>(msgA, tA, bgraph, wth, binput, msgB, tB, W_ma1);
    fused_iter<<<1024, 512, 0, stream>>>(msgB, tB, bgraph, wth, binput, msgA, tA, W_ma1);
    fused_iter<<<1024, 512, 0, stream>>>(msgA, tA, bgraph, wth, binput, msgB, tB, W_ma1);

    // atom stage
    atom_agg<<<N_ATOMS_C / 4, 256, 0, stream>>>(msgB, agraph, fatoms, ainput);
    gemm256<3><<<512, 256, 0, stream>>>(ainput, wto, atomh, nullptr, W_o_b, nullptr, nullptr, KPAD_O);

    // molecule attention
    gemm256<0><<<512, 256, 0, stream>>>(atomh, wta, hW, nullptr, nullptr, nullptr, nullptr, 256);
    mol_attn<<<N_MOLS, 256, 0, stream>>>(atomh, hW, zbuf);
    gemm256<3><<<512, 256, 0, stream>>>(zbuf, wtb, atth, nullptr, W_b_b, nullptr, nullptr, 256);

    final_reduce<<<N_MOLS, 256, 0, stream>>>(atomh, atth, out);
}

// Round 4
// 785.467 us; speedup vs baseline: 1.7441x; 1.7441x over previous
//
#include <hip/hip_runtime.h>

typedef unsigned short u16;
typedef __attribute__((ext_vector_type(8))) short short8;
typedef __attribute__((ext_vector_type(4))) float floatx4;

// ---------- bf16 helpers (RNE) ----------
__device__ __forceinline__ float bf2f(u16 u) {
    return __uint_as_float(((unsigned int)u) << 16);
}
__device__ __forceinline__ u16 f2bf(float f) {
    unsigned int i = __float_as_uint(f);
    unsigned int r = i + 0x7FFFu + ((i >> 16) & 1u);
    return (u16)(r >> 16);
}

// ---------- async global->LDS (16B per lane, wave-uniform LDS base) ----------
typedef __attribute__((address_space(3))) void lds_void;
typedef const __attribute__((address_space(1))) void g_void;
__device__ __forceinline__ void async_copy16(const void* g, void* l) {
    __builtin_amdgcn_global_load_lds((g_void*)g, (lds_void*)l, 16, 0, 0);
}

#define MFMA16(a, b, c) __builtin_amdgcn_mfma_f32_16x16x32_bf16(a, b, c, 0, 0, 0)

// ================= problem constants =================
#define E_BONDS 131072
#define N_ATOMS_C 65536
#define KPAD_I 160     // 157 padded
#define KPAD_O 416     // 399 padded
#define N_MOLS 2048

// epilogue slice: 16 rows x 264 u16 (528B stride, 16B-aligned rows, conflict-padded)
#define EPI_RSTR 264
#define EPI_SLICE_B 8448

// ================= prep kernels =================
__global__ __launch_bounds__(256) void prep_fbonds(const float* __restrict__ fb, u16* __restrict__ out) {
    int idx = blockIdx.x * 256 + threadIdx.x;           // E*160 total
    int row = idx / KPAD_I;
    int col = idx - row * KPAD_I;
    float v = (col < 157) ? fb[(size_t)row * 157 + col] : 0.f;
    out[idx] = f2bf(v);
}

// W [K,256] f32 -> Wt [256, Kpad] bf16 (transposed, zero-padded)
__global__ __launch_bounds__(256) void prep_wt(const float* __restrict__ W, u16* __restrict__ Wt, int K, int Kpad) {
    int idx = blockIdx.x * 256 + threadIdx.x;           // 256*Kpad total
    int n = idx / Kpad;
    int k = idx - n * Kpad;
    float v = (k < K) ? W[(size_t)k * 256 + n] : 0.f;
    Wt[idx] = f2bf(v);
}

// W_o_w [399,256] -> reordered transposed [256,416]
__global__ __launch_bounds__(256) void prep_wo(const float* __restrict__ W, u16* __restrict__ Wt) {
    int idx = blockIdx.x * 256 + threadIdx.x;           // 256*416 total
    int n = idx / KPAD_O;
    int k = idx - n * KPAD_O;
    float v = 0.f;
    if (k < 256)      v = W[(size_t)(143 + k) * 256 + n];
    else if (k < 399) v = W[(size_t)(k - 256) * 256 + n];
    Wt[idx] = f2bf(v);
}

// ================= MFMA GEMM, N=256 full width: C[M,256] = epi(A[M,K] @ Bt[256,K]^T) =================
// EPI: 0 plain->out ; 1 out2=pre, out=relu(pre), tout=relu.Wma score ; 3 out=relu(acc+bias)
// block: 256 thr (4 waves x 32 rows), M-tile 128. launch_bounds(256,2): 256-reg budget,
// acc 128 AGPR + ~84 VGPR fits with NO spill (VGPR+AGPR unified on gfx950).
template <int EPI>
__global__ __launch_bounds__(256, 2) void gemm256(
    const u16* __restrict__ A, const u16* __restrict__ Bt,
    u16* __restrict__ out, u16* __restrict__ out2,
    const float* __restrict__ bias, const float* __restrict__ wma,
    float* __restrict__ tout, int K)
{
    __shared__ char ldsbuf[33792];     // stage: Al 8192 + Bl 16384 = 24576 ; epi: 4 x 8448 = 33792
    u16* Al = (u16*)ldsbuf;
    u16* Bl = (u16*)(ldsbuf + 8192);

    const int tid = threadIdx.x;
    const int w = tid >> 6, lane = tid & 63;
    const int quad = lane >> 4, mr = lane & 15;
    const int m0 = blockIdx.x * 128;

    floatx4 acc[2][16] = {};

    for (int k0 = 0; k0 < K; k0 += 32) {
        {
            int c = tid;
            async_copy16(A + (size_t)(m0 + (c & 127)) * K + k0 + ((c >> 7) << 3), Al + c * 8);
            c = tid + 256;
            async_copy16(A + (size_t)(m0 + (c & 127)) * K + k0 + ((c >> 7) << 3), Al + c * 8);
        }
#pragma unroll
        for (int i = 0; i < 4; ++i) {
            int c = tid + i * 256;
            async_copy16(Bt + (size_t)(c & 255) * K + k0 + ((c >> 8) << 3), Bl + c * 8);
        }
        __syncthreads();

        short8 a0 = *(const short8*)(Al + quad * 1024 + (w * 32 + mr) * 8);
        short8 a1 = *(const short8*)(Al + quad * 1024 + (w * 32 + 16 + mr) * 8);
#pragma unroll
        for (int j = 0; j < 16; ++j) {
            short8 bf = *(const short8*)(Bl + quad * 2048 + (j * 16 + mr) * 8);
            acc[0][j] = MFMA16(a0, bf, acc[0][j]);
            acc[1][j] = MFMA16(a1, bf, acc[1][j]);
        }
        __syncthreads();
    }

    // ---- coalesced epilogue via per-wave LDS transpose ----
    u16* slice = (u16*)(ldsbuf + w * EPI_SLICE_B);
    const int lhalf = lane >> 5;
    const int lcol = (lane & 31) * 8;
    float wmal8[8];
    if (EPI == 1) {
#pragma unroll
        for (int e = 0; e < 8; ++e) wmal8[e] = wma[lcol + e];
    }
    float bl16[16];
    if (EPI == 3) {
#pragma unroll
        for (int j = 0; j < 16; ++j) bl16[j] = bias[j * 16 + mr];
    }

#pragma unroll
    for (int rg = 0; rg < 2; ++rg) {
#pragma unroll
        for (int j = 0; j < 16; ++j)
#pragma unroll
            for (int r = 0; r < 4; ++r) {
                float v = acc[rg][j][r];
                if (EPI == 3) { v += bl16[j]; v = v > 0.f ? v : 0.f; }
                slice[(quad * 4 + r) * EPI_RSTR + j * 16 + mr] = f2bf(v);
            }
#pragma unroll
        for (int round = 0; round < 8; ++round) {
            int rowl = round * 2 + lhalf;
            int row = m0 + w * 32 + rg * 16 + rowl;
            size_t off = (size_t)row * 256 + lcol;
            short8 pv = *(const short8*)(slice + rowl * EPI_RSTR + lcol);
            if (EPI == 0 || EPI == 3) {
                *(short8*)(out + off) = pv;
            } else {  // EPI 1
                *(short8*)(out2 + off) = pv;
                short8 rv; float p = 0.f;
#pragma unroll
                for (int e = 0; e < 8; ++e) {
                    u16 u = (u16)pv[e];
                    u = (u & 0x8000u) ? (u16)0 : u;     // relu in bf16 domain
                    rv[e] = (short)u;
                    p += bf2f(u) * wmal8[e];
                }
                *(short8*)(out + off) = rv;
                p += __shfl_xor(p, 1); p += __shfl_xor(p, 2); p += __shfl_xor(p, 4);
                p += __shfl_xor(p, 8); p += __shfl_xor(p, 16);
                if ((lane & 31) == 0) tout[row] = p;
            }
        }
    }
}

// ================= pure-BW gather iteration =================
// Mp = msg @ W_h (precomputed). msg_out[e] = relu(binput[e] + sum_j softmax(t[b_j]) * Mp[b_j])
// t_out[e] = msg_out[e] . wma.  2 bonds per wave (half-wave = 32 lanes x 8 cols = one 512B row).
// No LDS, ~45 VGPRs -> high occupancy; this is the memory-parallelism leg.
__global__ __launch_bounds__(256, 6) void gather_iter(
    const u16* __restrict__ Mp, const float* __restrict__ t_in,
    const int* __restrict__ bgraph, const u16* __restrict__ binput,
    u16* __restrict__ msg_out, float* __restrict__ t_out, const float* __restrict__ wma)
{
    const int w = threadIdx.x >> 6, lane = threadIdx.x & 63;
    const int half = lane >> 5, l32 = lane & 31;
    const int e = (blockIdx.x * 4 + w) * 2 + half;

    const int* bg = bgraph + (size_t)e * 6;
    int2 b01 = *(const int2*)bg;
    int2 b23 = *(const int2*)(bg + 2);
    int2 b45 = *(const int2*)(bg + 4);
    int b[6] = {b01.x, b01.y, b23.x, b23.y, b45.x, b45.y};

    float s[6];
#pragma unroll
    for (int j = 0; j < 6; ++j) s[j] = t_in[b[j]];
    float mx = fmaxf(fmaxf(fmaxf(s[0], s[1]), fmaxf(s[2], s[3])), fmaxf(s[4], s[5]));
    float wg[6]; float den = 0.f;
#pragma unroll
    for (int j = 0; j < 6; ++j) { wg[j] = __expf(s[j] - mx); den += wg[j]; }
    float inv = 1.f / den;
#pragma unroll
    for (int j = 0; j < 6; ++j) wg[j] *= inv;

    float a8[8] = {};
#pragma unroll
    for (int j = 0; j < 6; ++j) {
        uint4 u = *(const uint4*)(Mp + (size_t)b[j] * 256 + l32 * 8);
        float wj = wg[j];
        a8[0] += wj * __uint_as_float(u.x << 16);
        a8[1] += wj * __uint_as_float(u.x & 0xffff0000u);
        a8[2] += wj * __uint_as_float(u.y << 16);
        a8[3] += wj * __uint_as_float(u.y & 0xffff0000u);
        a8[4] += wj * __uint_as_float(u.z << 16);
        a8[5] += wj * __uint_as_float(u.z & 0xffff0000u);
        a8[6] += wj * __uint_as_float(u.w << 16);
        a8[7] += wj * __uint_as_float(u.w & 0xffff0000u);
    }

    size_t off = (size_t)e * 256 + l32 * 8;
    uint4 bi = *(const uint4*)(binput + off);
    float bv[8] = {
        __uint_as_float(bi.x << 16), __uint_as_float(bi.x & 0xffff0000u),
        __uint_as_float(bi.y << 16), __uint_as_float(bi.y & 0xffff0000u),
        __uint_as_float(bi.z << 16), __uint_as_float(bi.z & 0xffff0000u),
        __uint_as_float(bi.w << 16), __uint_as_float(bi.w & 0xffff0000u)};

    short8 mv; float p = 0.f;
#pragma unroll
    for (int k = 0; k < 8; ++k) {
        float v = a8[k] + bv[k];
        v = v > 0.f ? v : 0.f;
        u16 q = f2bf(v);
        mv[k] = (short)q;
        p += bf2f(q) * wma[l32 * 8 + k];
    }
    *(short8*)(msg_out + off) = mv;

    p += __shfl_xor(p, 1); p += __shfl_xor(p, 2); p += __shfl_xor(p, 4);
    p += __shfl_xor(p, 8); p += __shfl_xor(p, 16);
    if (l32 == 0) t_out[e] = p;
}

// ================= atom aggregation (2 atoms/wave, 16B loads) =================
// ainput [N,416] = [nei_a(256) | fatoms(143) | 0(17)]
__global__ __launch_bounds__(256, 6) void atom_agg(const u16* __restrict__ message, const int* __restrict__ agraph,
                                                   const float* __restrict__ fatoms, u16* __restrict__ ainput) {
    const int w = threadIdx.x >> 6, lane = threadIdx.x & 63;
    const int half = lane >> 5, l32 = lane & 31;
    const int a = (blockIdx.x * 4 + w) * 2 + half;

    const int* ag = agraph + (size_t)a * 6;
    int2 b01 = *(const int2*)ag;
    int2 b23 = *(const int2*)(ag + 2);
    int2 b45 = *(const int2*)(ag + 4);
    int b[6] = {b01.x, b01.y, b23.x, b23.y, b45.x, b45.y};

    float a8[8] = {};
#pragma unroll
    for (int j = 0; j < 6; ++j) {
        uint4 u = *(const uint4*)(message + (size_t)b[j] * 256 + l32 * 8);
        a8[0] += __uint_as_float(u.x << 16);
        a8[1] += __uint_as_float(u.x & 0xffff0000u);
        a8[2] += __uint_as_float(u.y << 16);
        a8[3] += __uint_as_float(u.y & 0xffff0000u);
        a8[4] += __uint_as_float(u.z << 16);
        a8[5] += __uint_as_float(u.z & 0xffff0000u);
        a8[6] += __uint_as_float(u.w << 16);
        a8[7] += __uint_as_float(u.w & 0xffff0000u);
    }
    u16* arow = ainput + (size_t)a * KPAD_O;
    short8 o;
#pragma unroll
    for (int k = 0; k < 8; ++k) o[k] = (short)f2bf(a8[k]);
    *(short8*)(arow + l32 * 8) = o;

    const float* frow = fatoms + (size_t)a * 143;
#pragma unroll
    for (int i = 0; i < 5; ++i) {
        int c = l32 + i * 32;
        arow[256 + c] = (c < 143) ? f2bf(frow[c]) : (u16)0;
    }
}

// ================= per-molecule self-attention: z = softmax(hW @ h^T) @ h =================
#define HSTR 260
__global__ __launch_bounds__(256) void mol_attn(const u16* __restrict__ atomh, const u16* __restrict__ hWg,
                                                u16* __restrict__ z) {
    __shared__ float hs[32 * HSTR];
    __shared__ float P[32 * 33];
    const int t = threadIdx.x;
    const int b = blockIdx.x;
    const u16* hbase = atomh + (size_t)b * 32 * 256;
    for (int e0 = t * 4; e0 < 8192; e0 += 1024) {
        int row = e0 >> 8, col = e0 & 255;
        ushort4 u = *(const ushort4*)(hbase + e0);
        floatx4 v; v.x = bf2f(u.x); v.y = bf2f(u.y); v.z = bf2f(u.z); v.w = bf2f(u.w);
        *(floatx4*)&hs[row * HSTR + col] = v;
    }
    __syncthreads();

    {
        int c = t & 31, a0 = t >> 5;
        const u16* hWb = hWg + (size_t)b * 32 * 256;
        for (int r = 0; r < 4; ++r) {
            int a = a0 + r * 8;
            const u16* hwrow = hWb + a * 256;
            float s = 0.f;
            for (int d = 0; d < 256; d += 4) {
                ushort4 u = *(const ushort4*)(hwrow + d);
                const float* hp = &hs[c * HSTR + d];
                s += bf2f(u.x) * hp[0] + bf2f(u.y) * hp[1] + bf2f(u.z) * hp[2] + bf2f(u.w) * hp[3];
            }
            P[a * 33 + c] = s;
        }
    }
    __syncthreads();
    if (t < 32) {
        float* prow = &P[t * 33];
        float mx = prow[0];
        for (int i = 1; i < 32; ++i) mx = fmaxf(mx, prow[i]);
        float den = 0.f;
        for (int i = 0; i < 32; ++i) { float ev = __expf(prow[i] - mx); prow[i] = ev; den += ev; }
        float inv = 1.f / den;
        for (int i = 0; i < 32; ++i) prow[i] *= inv;
    }
    __syncthreads();

    {
        int a = t >> 3, q = t & 7;
        floatx4 acc8[8];
#pragma unroll
        for (int i = 0; i < 8; ++i) acc8[i] = (floatx4){0.f, 0.f, 0.f, 0.f};
        const float* prow = &P[a * 33];
        for (int cc = 0; cc < 32; ++cc) {
            float p = prow[cc];
            const float* hrow = &hs[cc * HSTR + q * 4];
#pragma unroll
            for (int i = 0; i < 8; ++i) {
                floatx4 hv = *(const floatx4*)(hrow + i * 32);
                acc8[i] += p * hv;
            }
        }
        u16* zrow = z + ((size_t)b * 32 + a) * 256 + q * 4;
#pragma unroll
        for (int i = 0; i < 8; ++i) {
            ushort4 o;
            o.x = f2bf(acc8[i].x); o.y = f2bf(acc8[i].y); o.z = f2bf(acc8[i].z); o.w = f2bf(acc8[i].w);
            *(ushort4*)(zrow + i * 32) = o;
        }
    }
}

// ================= final: out[b,d] = sum_a (h + att_h) / 32 =================
__global__ __launch_bounds__(256) void final_reduce(const u16* __restrict__ atomh, const u16* __restrict__ atth,
                                                    float* __restrict__ out) {
    int idx = blockIdx.x * 256 + threadIdx.x;   // 2048*256
    int b = idx >> 8, d = idx & 255;
    const u16* ph = atomh + ((size_t)b * 32) * 256 + d;
    const u16* pa = atth + ((size_t)b * 32) * 256 + d;
    float s = 0.f;
#pragma unroll 4
    for (int a = 0; a < 32; ++a) s += bf2f(ph[a * 256]) + bf2f(pa[a * 256]);
    out[idx] = s * 0.03125f;
}

// ================= workspace layout (bytes) =================
#define O_FBP      ((size_t)0)                        // 41,943,040  fbp -> later atomh (33.5MB)
#define O_BINPUT   ((size_t)41943040)                 // 67,108,864  binput -> later hW (+0), zbuf (+33,554,432)
#define O_MSG      ((size_t)109051904)                // 67,108,864  msg (single buffer) -> later atth
#define O_MP       ((size_t)176160768)                // 67,108,864  M' = msg@W_h -> later ainput (54.5MB)
#define O_W        ((size_t)243269632)
#define O_WTI      (O_W)                              // 81,920
#define O_WTH      (O_W + 81920)                      // 131,072
#define O_WTO      (O_W + 212992)                     // 212,992
#define O_WTA      (O_W + 425984)                     // 131,072
#define O_WTB      (O_W + 557056)                     // 131,072
#define WS_NEED    ((size_t)243957760)

extern "C" void kernel_launch(void* const* d_in, const int* in_sizes, int n_in,
                              void* d_out, int out_size, void* d_ws, size_t ws_size,
                              hipStream_t stream) {
    const float* fatoms = (const float*)d_in[0];
    const float* fbonds = (const float*)d_in[1];
    const int*   agraph = (const int*)d_in[2];
    const int*   bgraph = (const int*)d_in[3];
    const float* W_i    = (const float*)d_in[5];
    const float* W_h    = (const float*)d_in[6];
    const float* W_o_w  = (const float*)d_in[7];
    const float* W_o_b  = (const float*)d_in[8];
    const float* W_a    = (const float*)d_in[9];
    const float* W_b_w  = (const float*)d_in[10];
    const float* W_b_b  = (const float*)d_in[11];
    const float* W_ma1  = (const float*)d_in[12];
    float* out = (float*)d_out;

    if (ws_size < WS_NEED) return;

    char* ws = (char*)d_ws;
    u16* fbp     = (u16*)(ws + O_FBP);
    u16* binput  = (u16*)(ws + O_BINPUT);
    u16* msg     = (u16*)(ws + O_MSG);
    u16* Mp      = (u16*)(ws + O_MP);
    u16* wti     = (u16*)(ws + O_WTI);
    u16* wth     = (u16*)(ws + O_WTH);
    u16* wto     = (u16*)(ws + O_WTO);
    u16* wta     = (u16*)(ws + O_WTA);
    u16* wtb     = (u16*)(ws + O_WTB);
    // aliases (dead-buffer reuse)
    u16* ainput  = (u16*)(ws + O_MP);       // M' dead after last gather; 54.5MB <= 67MB
    u16* atomh   = (u16*)(ws + O_FBP);      // fbp dead after binput GEMM; 33.5MB <= 42MB
    u16* hW      = (u16*)(ws + O_BINPUT);   // binput dead after iter3
    u16* zbuf    = (u16*)(ws + O_BINPUT + 33554432);
    u16* atth    = (u16*)(ws + O_MSG);      // msg dead after atom_agg
    // t score ping-pong lives in d_out (1MB of 2MB; overwritten by final_reduce)
    float* tA = (float*)d_out;
    float* tB = tA + E_BONDS;

    // prep
    prep_fbonds<<<81920, 256, 0, stream>>>(fbonds, fbp);
    prep_wt<<<160, 256, 0, stream>>>(W_i, wti, 157, KPAD_I);
    prep_wt<<<256, 256, 0, stream>>>(W_h, wth, 256, 256);
    prep_wo<<<416, 256, 0, stream>>>(W_o_w, wto);
    prep_wt<<<256, 256, 0, stream>>>(W_a, wta, 256, 256);
    prep_wt<<<256, 256, 0, stream>>>(W_b_w, wtb, 256, 256);

    // binput = fbonds @ W_i ; msg0 = relu(binput) ; t0 = msg0 . Wma
    gemm256<1><<<1024, 256, 0, stream>>>(fbp, wti, msg, binput, nullptr, W_ma1, tA, KPAD_I);

    // 3 message-passing iterations, split into dense GEMM + pure-BW gather
    // iter 1
    gemm256<0><<<1024, 256, 0, stream>>>(msg, wth, Mp, nullptr, nullptr, nullptr, nullptr, 256);
    gather_iter<<<E_BONDS / 8, 256, 0, stream>>>(Mp, tA, bgraph, binput, msg, tB, W_ma1);
    // iter 2
    gemm256<0><<<1024, 256, 0, stream>>>(msg, wth, Mp, nullptr, nullptr, nullptr, nullptr, 256);
    gather_iter<<<E_BONDS / 8, 256, 0, stream>>>(Mp, tB, bgraph, binput, msg, tA, W_ma1);
    // iter 3
    gemm256<0><<<1024, 256, 0, stream>>>(msg, wth, Mp, nullptr, nullptr, nullptr, nullptr, 256);
    gather_iter<<<E_BONDS / 8, 256, 0, stream>>>(Mp, tA, bgraph, binput, msg, tB, W_ma1);

    // atom stage
    atom_agg<<<N_ATOMS_C / 8, 256, 0, stream>>>(msg, agraph, fatoms, ainput);
    gemm256<3><<<512, 256, 0, stream>>>(ainput, wto, atomh, nullptr, W_o_b, nullptr, nullptr, KPAD_O);

    // molecule attention
    gemm256<0><<<512, 256, 0, stream>>>(atomh, wta, hW, nullptr, nullptr, nullptr, nullptr, 256);
    mol_attn<<<N_MOLS, 256, 0, stream>>>(atomh, hW, zbuf);
    gemm256<3><<<512, 256, 0, stream>>>(zbuf, wtb, atth, nullptr, W_b_b, nullptr, nullptr, 256);

    final_reduce<<<N_MOLS, 256, 0, stream>>>(atomh, atth, out);
}

// Round 5
// 784.165 us; speedup vs baseline: 1.7470x; 1.0017x over previous
//
#include <hip/hip_runtime.h>

typedef unsigned short u16;
typedef __attribute__((ext_vector_type(8))) short short8;
typedef __attribute__((ext_vector_type(4))) float floatx4;

// ---------- bf16 helpers (RNE) ----------
__device__ __forceinline__ float bf2f(u16 u) {
    return __uint_as_float(((unsigned int)u) << 16);
}
__device__ __forceinline__ u16 f2bf(float f) {
    unsigned int i = __float_as_uint(f);
    unsigned int r = i + 0x7FFFu + ((i >> 16) & 1u);
    return (u16)(r >> 16);
}
// relu on two packed bf16 (zero halves with sign bit set)
__device__ __forceinline__ unsigned int relu2(unsigned int x) {
    unsigned int m = (((x >> 15) & 1u) * 0x0000FFFFu) | ((x >> 31) * 0xFFFF0000u);
    return x & ~m;
}

// ---------- async global->LDS (16B per lane, wave-uniform LDS base) ----------
typedef __attribute__((address_space(3))) void lds_void;
typedef const __attribute__((address_space(1))) void g_void;
__device__ __forceinline__ void async_copy16(const void* g, void* l) {
    __builtin_amdgcn_global_load_lds((g_void*)g, (lds_void*)l, 16, 0, 0);
}

#define MFMA16(a, b, c) __builtin_amdgcn_mfma_f32_16x16x32_bf16(a, b, c, 0, 0, 0)

// ================= problem constants =================
#define E_BONDS 131072
#define N_ATOMS_C 65536
#define KPAD_I 160     // 157 padded
#define KPAD_O 416     // 399 padded
#define N_MOLS 2048

// ================= prep kernels =================
__global__ __launch_bounds__(256) void prep_fbonds(const float* __restrict__ fb, u16* __restrict__ out) {
    int idx = blockIdx.x * 256 + threadIdx.x;           // E*160 total
    int row = idx / KPAD_I;
    int col = idx - row * KPAD_I;
    float v = (col < 157) ? fb[(size_t)row * 157 + col] : 0.f;
    out[idx] = f2bf(v);
}

// W [K,256] f32 -> Wt [256, Kpad] bf16 (transposed, zero-padded)
__global__ __launch_bounds__(256) void prep_wt(const float* __restrict__ W, u16* __restrict__ Wt, int K, int Kpad) {
    int idx = blockIdx.x * 256 + threadIdx.x;           // 256*Kpad total
    int n = idx / Kpad;
    int k = idx - n * Kpad;
    float v = (k < K) ? W[(size_t)k * 256 + n] : 0.f;
    Wt[idx] = f2bf(v);
}

// W_o_w [399,256] -> reordered transposed [256,416]
__global__ __launch_bounds__(256) void prep_wo(const float* __restrict__ W, u16* __restrict__ Wt) {
    int idx = blockIdx.x * 256 + threadIdx.x;           // 256*416 total
    int n = idx / KPAD_O;
    int k = idx - n * KPAD_O;
    float v = 0.f;
    if (k < 256)      v = W[(size_t)(143 + k) * 256 + n];
    else if (k < 399) v = W[(size_t)(k - 256) * 256 + n];
    Wt[idx] = f2bf(v);
}

// ================= MFMA GEMM, N=256 full width: C[M,256] = epi(A[M,K] @ Bt[256,K]^T) =================
// EPI: 0 plain->out ; 1 out=pre, tout=relu(pre).wma score ; 3 out=relu(acc+bias)
// RELUA: apply bf16-relu to A during staging (VGPR-staged instead of DMA).
// 512 thr = 8 waves x 16 rows; M-tile 128; acc[16] = 64 AGPR/wave.
// launch_bounds(512,3): 168-reg unified budget; ~150 used -> 24 waves/CU (75% occ).
template <int EPI, bool RELUA>
__global__ __launch_bounds__(512, 3) void gemm256(
    const u16* __restrict__ A, const u16* __restrict__ Bt,
    u16* __restrict__ out,
    const float* __restrict__ bias, const float* __restrict__ wma,
    float* __restrict__ tout, int K)
{
    __shared__ char ldsbuf[33792];     // stage: Al 8192 + Bl 16384 = 24576 ; epi: 8 waves x 4224
    u16* Al = (u16*)ldsbuf;            // [kb=4][row=128][8]
    u16* Bl = (u16*)(ldsbuf + 8192);   // [kb=4][n=256][8]

    const int tid = threadIdx.x;
    const int w = tid >> 6, lane = tid & 63;
    const int quad = lane >> 4, mr = lane & 15;
    const int m0 = blockIdx.x * 128;

    floatx4 acc[16] = {};

    // A chunk for this thread: kb = tid>>7, row = tid&127 ; lds offset = tid*16B (wave-uniform+lane*16)
    const u16* Ag = A + (size_t)(m0 + (tid & 127)) * K + ((tid >> 7) << 3);

    for (int k0 = 0; k0 < K; k0 += 32) {
        if (RELUA) {
            uint4 x = *(const uint4*)(Ag + k0);
            x.x = relu2(x.x); x.y = relu2(x.y); x.z = relu2(x.z); x.w = relu2(x.w);
            *(uint4*)(Al + tid * 8) = x;
        } else {
            async_copy16(Ag + k0, Al + tid * 8);
        }
#pragma unroll
        for (int i = 0; i < 2; ++i) {
            int c = tid + i * 512;
            async_copy16(Bt + (size_t)(c & 255) * K + k0 + ((c >> 8) << 3), Bl + c * 8);
        }
        __syncthreads();

        short8 af = *(const short8*)(Al + quad * 1024 + (w * 16 + mr) * 8);
#pragma unroll
        for (int j = 0; j < 16; ++j) {
            short8 bf = *(const short8*)(Bl + quad * 2048 + (j * 16 + mr) * 8);
            acc[j] = MFMA16(af, bf, acc[j]);
        }
        __syncthreads();
    }

    // ---- coalesced epilogue: two 8-row passes through a wave-private LDS slice ----
    u16* slice = (u16*)ldsbuf + w * 2112;       // 8 rows x 264 u16 = 4224 B
    const int lhalf = lane >> 5;
    const int lcol = (lane & 31) * 8;
    float wmal8[8];
    if (EPI == 1) {
#pragma unroll
        for (int e = 0; e < 8; ++e) wmal8[e] = wma[lcol + e];
    }
    float bl16[16];
    if (EPI == 3) {
#pragma unroll
        for (int j = 0; j < 16; ++j) bl16[j] = bias[j * 16 + mr];
    }

#pragma unroll
    for (int p = 0; p < 2; ++p) {
        // scatter: quads {2p, 2p+1} own local rows 0..7 of this pass
        if ((quad >> 1) == p) {
            int lr = (quad & 1) * 4;
#pragma unroll
            for (int j = 0; j < 16; ++j)
#pragma unroll
                for (int r = 0; r < 4; ++r) {
                    float v = acc[j][r];
                    if (EPI == 3) { v += bl16[j]; v = v > 0.f ? v : 0.f; }
                    slice[(lr + r) * 264 + j * 16 + mr] = f2bf(v);
                }
        }
        __syncthreads();
        // contiguous readback + 16B stores (2 rows per round, half-wave per row)
#pragma unroll
        for (int round = 0; round < 4; ++round) {
            int rowl = round * 2 + lhalf;
            int row = m0 + w * 16 + p * 8 + rowl;
            size_t off = (size_t)row * 256 + lcol;
            short8 pv = *(const short8*)(slice + rowl * 264 + lcol);
            if (EPI == 0 || EPI == 3) {
                *(short8*)(out + off) = pv;
            } else {   // EPI 1: store pre; score from relu(pre)
                *(short8*)(out + off) = pv;
                float pdot = 0.f;
#pragma unroll
                for (int e = 0; e < 8; ++e) {
                    u16 u = (u16)pv[e];
                    u = (u & 0x8000u) ? (u16)0 : u;
                    pdot += bf2f(u) * wmal8[e];
                }
                pdot += __shfl_xor(pdot, 1); pdot += __shfl_xor(pdot, 2);
                pdot += __shfl_xor(pdot, 4); pdot += __shfl_xor(pdot, 8);
                pdot += __shfl_xor(pdot, 16);
                if ((lane & 31) == 0) tout[row] = pdot;
            }
        }
        __syncthreads();
    }
}

// ================= pure-BW gather iteration =================
// Mp = relu(msg) @ W_h (precomputed). msg_out[e] = relu(binput[e] + sum_j softmax(t[b_j]) * Mp[b_j])
// t_out[e] = msg_out[e] . wma.  2 bonds per wave.
__global__ __launch_bounds__(256, 6) void gather_iter(
    const u16* __restrict__ Mp, const float* __restrict__ t_in,
    const int* __restrict__ bgraph, const u16* __restrict__ binput,
    u16* __restrict__ msg_out, float* __restrict__ t_out, const float* __restrict__ wma)
{
    const int w = threadIdx.x >> 6, lane = threadIdx.x & 63;
    const int half = lane >> 5, l32 = lane & 31;
    const int e = (blockIdx.x * 4 + w) * 2 + half;

    const int* bg = bgraph + (size_t)e * 6;
    int2 b01 = *(const int2*)bg;
    int2 b23 = *(const int2*)(bg + 2);
    int2 b45 = *(const int2*)(bg + 4);
    int b[6] = {b01.x, b01.y, b23.x, b23.y, b45.x, b45.y};

    float s[6];
#pragma unroll
    for (int j = 0; j < 6; ++j) s[j] = t_in[b[j]];
    float mx = fmaxf(fmaxf(fmaxf(s[0], s[1]), fmaxf(s[2], s[3])), fmaxf(s[4], s[5]));
    float wg[6]; float den = 0.f;
#pragma unroll
    for (int j = 0; j < 6; ++j) { wg[j] = __expf(s[j] - mx); den += wg[j]; }
    float inv = 1.f / den;
#pragma unroll
    for (int j = 0; j < 6; ++j) wg[j] *= inv;

    float a8[8] = {};
#pragma unroll
    for (int j = 0; j < 6; ++j) {
        uint4 u = *(const uint4*)(Mp + (size_t)b[j] * 256 + l32 * 8);
        float wj = wg[j];
        a8[0] += wj * __uint_as_float(u.x << 16);
        a8[1] += wj * __uint_as_float(u.x & 0xffff0000u);
        a8[2] += wj * __uint_as_float(u.y << 16);
        a8[3] += wj * __uint_as_float(u.y & 0xffff0000u);
        a8[4] += wj * __uint_as_float(u.z << 16);
        a8[5] += wj * __uint_as_float(u.z & 0xffff0000u);
        a8[6] += wj * __uint_as_float(u.w << 16);
        a8[7] += wj * __uint_as_float(u.w & 0xffff0000u);
    }

    size_t off = (size_t)e * 256 + l32 * 8;
    uint4 bi = *(const uint4*)(binput + off);
    float bv[8] = {
        __uint_as_float(bi.x << 16), __uint_as_float(bi.x & 0xffff0000u),
        __uint_as_float(bi.y << 16), __uint_as_float(bi.y & 0xffff0000u),
        __uint_as_float(bi.z << 16), __uint_as_float(bi.z & 0xffff0000u),
        __uint_as_float(bi.w << 16), __uint_as_float(bi.w & 0xffff0000u)};

    short8 mv; float p = 0.f;
#pragma unroll
    for (int k = 0; k < 8; ++k) {
        float v = a8[k] + bv[k];
        v = v > 0.f ? v : 0.f;
        u16 q = f2bf(v);
        mv[k] = (short)q;
        p += bf2f(q) * wma[l32 * 8 + k];
    }
    *(short8*)(msg_out + off) = mv;

    p += __shfl_xor(p, 1); p += __shfl_xor(p, 2); p += __shfl_xor(p, 4);
    p += __shfl_xor(p, 8); p += __shfl_xor(p, 16);
    if (l32 == 0) t_out[e] = p;
}

// ================= atom aggregation (2 atoms/wave, 16B loads) =================
// ainput [N,416] = [nei_a(256) | fatoms(143) | 0(17)]
__global__ __launch_bounds__(256, 6) void atom_agg(const u16* __restrict__ message, const int* __restrict__ agraph,
                                                   const float* __restrict__ fatoms, u16* __restrict__ ainput) {
    const int w = threadIdx.x >> 6, lane = threadIdx.x & 63;
    const int half = lane >> 5, l32 = lane & 31;
    const int a = (blockIdx.x * 4 + w) * 2 + half;

    const int* ag = agraph + (size_t)a * 6;
    int2 b01 = *(const int2*)ag;
    int2 b23 = *(const int2*)(ag + 2);
    int2 b45 = *(const int2*)(ag + 4);
    int b[6] = {b01.x, b01.y, b23.x, b23.y, b45.x, b45.y};

    float a8[8] = {};
#pragma unroll
    for (int j = 0; j < 6; ++j) {
        uint4 u = *(const uint4*)(message + (size_t)b[j] * 256 + l32 * 8);
        a8[0] += __uint_as_float(u.x << 16);
        a8[1] += __uint_as_float(u.x & 0xffff0000u);
        a8[2] += __uint_as_float(u.y << 16);
        a8[3] += __uint_as_float(u.y & 0xffff0000u);
        a8[4] += __uint_as_float(u.z << 16);
        a8[5] += __uint_as_float(u.z & 0xffff0000u);
        a8[6] += __uint_as_float(u.w << 16);
        a8[7] += __uint_as_float(u.w & 0xffff0000u);
    }
    u16* arow = ainput + (size_t)a * KPAD_O;
    short8 o;
#pragma unroll
    for (int k = 0; k < 8; ++k) o[k] = (short)f2bf(a8[k]);
    *(short8*)(arow + l32 * 8) = o;

    const float* frow = fatoms + (size_t)a * 143;
#pragma unroll
    for (int i = 0; i < 5; ++i) {
        int c = l32 + i * 32;
        arow[256 + c] = (c < 143) ? f2bf(frow[c]) : (u16)0;
    }
}

// ================= per-molecule self-attention: z = softmax(hW @ h^T) @ h =================
#define HSTR 260
__global__ __launch_bounds__(256) void mol_attn(const u16* __restrict__ atomh, const u16* __restrict__ hWg,
                                                u16* __restrict__ z) {
    __shared__ float hs[32 * HSTR];
    __shared__ float P[32 * 33];
    const int t = threadIdx.x;
    const int b = blockIdx.x;
    const u16* hbase = atomh + (size_t)b * 32 * 256;
    for (int e0 = t * 4; e0 < 8192; e0 += 1024) {
        int row = e0 >> 8, col = e0 & 255;
        ushort4 u = *(const ushort4*)(hbase + e0);
        floatx4 v; v.x = bf2f(u.x); v.y = bf2f(u.y); v.z = bf2f(u.z); v.w = bf2f(u.w);
        *(floatx4*)&hs[row * HSTR + col] = v;
    }
    __syncthreads();

    {
        int c = t & 31, a0 = t >> 5;
        const u16* hWb = hWg + (size_t)b * 32 * 256;
        for (int r = 0; r < 4; ++r) {
            int a = a0 + r * 8;
            const u16* hwrow = hWb + a * 256;
            float s = 0.f;
            for (int d = 0; d < 256; d += 4) {
                ushort4 u = *(const ushort4*)(hwrow + d);
                const float* hp = &hs[c * HSTR + d];
                s += bf2f(u.x) * hp[0] + bf2f(u.y) * hp[1] + bf2f(u.z) * hp[2] + bf2f(u.w) * hp[3];
            }
            P[a * 33 + c] = s;
        }
    }
    __syncthreads();
    if (t < 32) {
        float* prow = &P[t * 33];
        float mx = prow[0];
        for (int i = 1; i < 32; ++i) mx = fmaxf(mx, prow[i]);
        float den = 0.f;
        for (int i = 0; i < 32; ++i) { float ev = __expf(prow[i] - mx); prow[i] = ev; den += ev; }
        float inv = 1.f / den;
        for (int i = 0; i < 32; ++i) prow[i] *= inv;
    }
    __syncthreads();

    {
        int a = t >> 3, q = t & 7;
        floatx4 acc8[8];
#pragma unroll
        for (int i = 0; i < 8; ++i) acc8[i] = (floatx4){0.f, 0.f, 0.f, 0.f};
        const float* prow = &P[a * 33];
        for (int cc = 0; cc < 32; ++cc) {
            float p = prow[cc];
            const float* hrow = &hs[cc * HSTR + q * 4];
#pragma unroll
            for (int i = 0; i < 8; ++i) {
                floatx4 hv = *(const floatx4*)(hrow + i * 32);
                acc8[i] += p * hv;
            }
        }
        u16* zrow = z + ((size_t)b * 32 + a) * 256 + q * 4;
#pragma unroll
        for (int i = 0; i < 8; ++i) {
            ushort4 o;
            o.x = f2bf(acc8[i].x); o.y = f2bf(acc8[i].y); o.z = f2bf(acc8[i].z); o.w = f2bf(acc8[i].w);
            *(ushort4*)(zrow + i * 32) = o;
        }
    }
}

// ================= final: out[b,d] = sum_a (h + att_h) / 32 =================
__global__ __launch_bounds__(256) void final_reduce(const u16* __restrict__ atomh, const u16* __restrict__ atth,
                                                    float* __restrict__ out) {
    int idx = blockIdx.x * 256 + threadIdx.x;   // 2048*256
    int b = idx >> 8, d = idx & 255;
    const u16* ph = atomh + ((size_t)b * 32) * 256 + d;
    const u16* pa = atth + ((size_t)b * 32) * 256 + d;
    float s = 0.f;
#pragma unroll 4
    for (int a = 0; a < 32; ++a) s += bf2f(ph[a * 256]) + bf2f(pa[a * 256]);
    out[idx] = s * 0.03125f;
}

// ================= workspace layout (bytes) =================
#define O_FBP      ((size_t)0)                        // 41,943,040  fbp -> later atomh (33.5MB)
#define O_BINPUT   ((size_t)41943040)                 // 67,108,864  binput -> later hW (+0), zbuf (+33,554,432)
#define O_MSG      ((size_t)109051904)                // 67,108,864  msg -> later atth
#define O_MP       ((size_t)176160768)                // 67,108,864  M' -> later ainput (54.5MB)
#define O_W        ((size_t)243269632)
#define O_WTI      (O_W)                              // 81,920
#define O_WTH      (O_W + 81920)                      // 131,072
#define O_WTO      (O_W + 212992)                     // 212,992
#define O_WTA      (O_W + 425984)                     // 131,072
#define O_WTB      (O_W + 557056)                     // 131,072
#define WS_NEED    ((size_t)243957760)

extern "C" void kernel_launch(void* const* d_in, const int* in_sizes, int n_in,
                              void* d_out, int out_size, void* d_ws, size_t ws_size,
                              hipStream_t stream) {
    const float* fatoms = (const float*)d_in[0];
    const float* fbonds = (const float*)d_in[1];
    const int*   agraph = (const int*)d_in[2];
    const int*   bgraph = (const int*)d_in[3];
    const float* W_i    = (const float*)d_in[5];
    const float* W_h    = (const float*)d_in[6];
    const float* W_o_w  = (const float*)d_in[7];
    const float* W_o_b  = (const float*)d_in[8];
    const float* W_a    = (const float*)d_in[9];
    const float* W_b_w  = (const float*)d_in[10];
    const float* W_b_b  = (const float*)d_in[11];
    const float* W_ma1  = (const float*)d_in[12];
    float* out = (float*)d_out;

    if (ws_size < WS_NEED) return;

    char* ws = (char*)d_ws;
    u16* fbp     = (u16*)(ws + O_FBP);
    u16* binput  = (u16*)(ws + O_BINPUT);
    u16* msg     = (u16*)(ws + O_MSG);
    u16* Mp      = (u16*)(ws + O_MP);
    u16* wti     = (u16*)(ws + O_WTI);
    u16* wth     = (u16*)(ws + O_WTH);
    u16* wto     = (u16*)(ws + O_WTO);
    u16* wta     = (u16*)(ws + O_WTA);
    u16* wtb     = (u16*)(ws + O_WTB);
    // aliases (dead-buffer reuse)
    u16* ainput  = (u16*)(ws + O_MP);       // M' dead after last gather
    u16* atomh   = (u16*)(ws + O_FBP);      // fbp dead after binput GEMM
    u16* hW      = (u16*)(ws + O_BINPUT);   // binput dead after iter3
    u16* zbuf    = (u16*)(ws + O_BINPUT + 33554432);
    u16* atth    = (u16*)(ws + O_MSG);      // msg dead after atom_agg
    // t score ping-pong lives in d_out (1MB of 2MB; overwritten by final_reduce)
    float* tA = (float*)d_out;
    float* tB = tA + E_BONDS;

    // prep
    prep_fbonds<<<81920, 256, 0, stream>>>(fbonds, fbp);
    prep_wt<<<160, 256, 0, stream>>>(W_i, wti, 157, KPAD_I);
    prep_wt<<<256, 256, 0, stream>>>(W_h, wth, 256, 256);
    prep_wo<<<416, 256, 0, stream>>>(W_o_w, wto);
    prep_wt<<<256, 256, 0, stream>>>(W_a, wta, 256, 256);
    prep_wt<<<256, 256, 0, stream>>>(W_b_w, wtb, 256, 256);

    // binput = fbonds @ W_i (pre-relu stored) ; t0 = relu(binput) . Wma
    gemm256<1, false><<<1024, 512, 0, stream>>>(fbp, wti, binput, nullptr, W_ma1, tA, KPAD_I);

    // iter 1: Mp = relu(binput) @ W_h  (msg0 never materialized)
    gemm256<0, true><<<1024, 512, 0, stream>>>(binput, wth, Mp, nullptr, nullptr, nullptr, 256);
    gather_iter<<<E_BONDS / 8, 256, 0, stream>>>(Mp, tA, bgraph, binput, msg, tB, W_ma1);
    // iter 2
    gemm256<0, false><<<1024, 512, 0, stream>>>(msg, wth, Mp, nullptr, nullptr, nullptr, 256);
    gather_iter<<<E_BONDS / 8, 256, 0, stream>>>(Mp, tB, bgraph, binput, msg, tA, W_ma1);
    // iter 3
    gemm256<0, false><<<1024, 512, 0, stream>>>(msg, wth, Mp, nullptr, nullptr, nullptr, 256);
    gather_iter<<<E_BONDS / 8, 256, 0, stream>>>(Mp, tA, bgraph, binput, msg, tB, W_ma1);

    // atom stage
    atom_agg<<<N_ATOMS_C / 8, 256, 0, stream>>>(msg, agraph, fatoms, ainput);
    gemm256<3, false><<<512, 512, 0, stream>>>(ainput, wto, atomh, W_o_b, nullptr, nullptr, KPAD_O);

    // molecule attention
    gemm256<0, false><<<512, 512, 0, stream>>>(atomh, wta, hW, nullptr, nullptr, nullptr, 256);
    mol_attn<<<N_MOLS, 256, 0, stream>>>(atomh, hW, zbuf);
    gemm256<3, false><<<512, 512, 0, stream>>>(zbuf, wtb, atth, W_b_b, nullptr, nullptr, 256);

    final_reduce<<<N_MOLS, 256, 0, stream>>>(atomh, atth, out);
}